// Round 3
// baseline (116.707 us; speedup 1.0000x reference)
//
#include <hip/hip_runtime.h>

// LocallyConnected2d: out[b,o,p,q] = sum_{i,kh,kw} x[b,i,2p+kh,2q+kw] * w[o,i,p,q,kh*3+kw]
// x: (8,32,64,64) f32, w: (1,32,32,31,31,9) f32, out: (8,32,31,31) f32
//
// Block = (p, og) with og = o-pair (16 groups of 2 o). 512 threads = 32 q-lanes x 16 ic.
// Two i-halves per block; per half, thread handles i = h*16+ic (1 i), 2 o, 8 b.
// Weights staged global->LDS via global_load_lds (dense lane-linear dword stream,
// each weight line requested ~once vs ~18x for the old stride-36 scalar loads).
// LDS seg stride padded 279->288 so the LDS index is linear in the flat thread
// stream (global_load_lds needs uniform-base + lane*4); pad words never read.
// Reduction scratch aliases the weight buffer (union) after the last w read.

#define CIN 32
#define COUT 32
#define HH 64
#define WW 64
#define HO 31
#define WO 31
#define XB 131072   // x batch stride (floats)
#define WSEG 279    // 31*9 floats per (o,i,p) segment in global
#define WPAD 288    // padded seg stride in LDS (32*9)
#define WOI 8649    // 961*9 = weight (o,i) stride in floats

#define GLD_LDS(gp, lp)                                              \
    __builtin_amdgcn_global_load_lds(                                \
        (const __attribute__((address_space(1))) void*)(gp),         \
        (__attribute__((address_space(3))) void*)(lp), 4, 0, 0)

__global__ __launch_bounds__(512, 4) void lc2d_kernel(const float* __restrict__ x,
                                                      const float* __restrict__ wgt,
                                                      float* __restrict__ out) {
    __shared__ union {
        float w[32 * WPAD];       // 9216 floats: [seg 0..31][288], seg = lo*16 + ic
        float red[16][32][17];    // 8704 floats, aliased after last w read
    } sm;

    const int t = threadIdx.x;
    const int qlane = t & 31;
    const int ic = t >> 5;                   // 0..15
    const int p  = blockIdx.x >> 4;          // 0..30
    const int og = blockIdx.x & 15;          // 0..15
    const int q  = (qlane < 31) ? qlane : 30;  // clamp dup lane (never stored)
    const int o0 = og * 2;

    float acc[2][8];
#pragma unroll
    for (int lo = 0; lo < 2; ++lo)
#pragma unroll
        for (int b = 0; b < 8; ++b) acc[lo][b] = 0.f;

    const float* xq = x + 2 * q;
    const int ldsWaveBase = t & ~63;         // wave-uniform

    for (int h = 0; h < 2; ++h) {
        if (h) __syncthreads();              // prev compute's LDS reads done

        // ---- stage w[o0..o0+1][h*16..h*16+15][p][*][*] into LDS, lane-linear ----
#pragma unroll
        for (int j = 0; j < 18; ++j) {
            const int f = t + j * 512;       // 0..9215, linear LDS word index
            const int u = f >> 5;            // 0..287
            const int seg = u / 9;           // 0..31 (lo*16 + ii)
            int off = f - seg * WPAD;        // 0..287 within padded seg
            if (off > WSEG - 1) off = WSEG - 1;  // pad lanes dup-load, never read
            const int oi = o0 * CIN + h * 16 + seg + (seg & 16);  // (o0+lo)*32 + h*16 + ii
            const float* gp = wgt + (size_t)oi * WOI + p * WSEG + off;
            GLD_LDS(gp, &sm.w[j * 512 + ldsWaveBase]);
        }
        __syncthreads();                     // drains vmcnt -> staging visible

        // ---- compute: i = h*16 + ic ----
        const int i = h * 16 + ic;
        float wv[2][9];
        const int wb0 = ic * WPAD + q * 9;
        const int wb1 = (16 + ic) * WPAD + q * 9;
#pragma unroll
        for (int k = 0; k < 9; ++k) {
            wv[0][k] = sm.w[wb0 + k];
            wv[1][k] = sm.w[wb1 + k];
        }

        const float* xrow0 = xq + ((size_t)i * HH + 2 * p) * WW;
#pragma unroll
        for (int kh = 0; kh < 3; ++kh) {
            const float* xr = xrow0 + kh * WW;
#pragma unroll
            for (int b = 0; b < 8; ++b) {
                const float* xb = xr + (size_t)b * XB;
                const float2 a = *reinterpret_cast<const float2*>(xb);      // 2q,2q+1
                const float2 c = *reinterpret_cast<const float2*>(xb + 2);  // 2q+2,2q+3
#pragma unroll
                for (int lo = 0; lo < 2; ++lo)
                    acc[lo][b] += wv[lo][kh * 3 + 0] * a.x
                                + wv[lo][kh * 3 + 1] * a.y
                                + wv[lo][kh * 3 + 2] * c.x;
            }
        }
    }

    __syncthreads();                         // last w reads done before aliasing

    // ---- reduce 16 ic-partials per (q, lo, b) ----
#pragma unroll
    for (int lo = 0; lo < 2; ++lo)
#pragma unroll
        for (int b = 0; b < 8; ++b)
            sm.red[ic][qlane][lo * 8 + b] = acc[lo][b];
    __syncthreads();

    if (t < 496) {                           // 16 e x 31 q
        const int e  = t / 31;               // e = lo*8 + b
        const int qq = t - e * 31;
        float s = 0.f;
#pragma unroll
        for (int icc = 0; icc < 16; ++icc) s += sm.red[icc][qq][e];
        const int lo = e >> 3, b = e & 7;
        out[(((size_t)b * COUT + o0 + lo) * HO + p) * WO + qq] = s;
    }
}

extern "C" void kernel_launch(void* const* d_in, const int* in_sizes, int n_in,
                              void* d_out, int out_size, void* d_ws, size_t ws_size,
                              hipStream_t stream) {
    const float* x = (const float*)d_in[0];
    const float* w = (const float*)d_in[1];
    float* out = (float*)d_out;
    lc2d_kernel<<<dim3(HO * 16), dim3(512), 0, stream>>>(x, w, out);  // 31 p x 16 og
}

// Round 4
// 85.975 us; speedup vs baseline: 1.3574x; 1.3574x over previous
//
#include <hip/hip_runtime.h>

// LocallyConnected2d: out[b,o,p,q] = sum_{i,kh,kw} x[b,i,2p+kh,2q+kw] * w[o,i,p,q,kh*3+kw]
// x: (8,32,64,64) f32, w: (1,32,32,31,31,9) f32, out: (8,32,31,31) f32
//
// Block = (p, og) with og = o-pair (16 groups of 2 o). 512 threads = 32 q-lanes x 16 ic.
// Two i-halves per block; per half, thread handles i = h*16+ic (1 i), 2 o, 8 b.
// Weights staged global->LDS via global_load_lds (dense lane-linear dword stream,
// each weight line requested ~once vs ~18x for stride-36 scalar loads).
// LDS seg stride padded 279->288 so the LDS index is linear in the flat thread
// stream (global_load_lds needs uniform-base + lane*4); pad words never read.
// Reduction scratch aliases the weight buffer (union) after the last w read.
//
// __launch_bounds__(512, 2): R3's (512,4) was treated as 4 blocks/CU -> VGPR
// capped at 64 -> 73 MB of scratch spill (WRITE_SIZE counter). (512,2) caps at
// >=128 VGPR under either arg2 interpretation -> no spill, 2 blocks/CU.

#define CIN 32
#define COUT 32
#define HH 64
#define WW 64
#define HO 31
#define WO 31
#define XB 131072   // x batch stride (floats)
#define WSEG 279    // 31*9 floats per (o,i,p) segment in global
#define WPAD 288    // padded seg stride in LDS (32*9)
#define WOI 8649    // 961*9 = weight (o,i) stride in floats

#define GLD_LDS(gp, lp)                                              \
    __builtin_amdgcn_global_load_lds(                                \
        (const __attribute__((address_space(1))) void*)(gp),         \
        (__attribute__((address_space(3))) void*)(lp), 4, 0, 0)

__global__ __launch_bounds__(512, 2) void lc2d_kernel(const float* __restrict__ x,
                                                      const float* __restrict__ wgt,
                                                      float* __restrict__ out) {
    __shared__ union {
        float w[32 * WPAD];       // 9216 floats: [seg 0..31][288], seg = lo*16 + ic
        float red[16][32][17];    // 8704 floats, aliased after last w read
    } sm;

    const int t = threadIdx.x;
    const int qlane = t & 31;
    const int ic = t >> 5;                   // 0..15
    const int p  = blockIdx.x >> 4;          // 0..30
    const int og = blockIdx.x & 15;          // 0..15
    const int q  = (qlane < 31) ? qlane : 30;  // clamp dup lane (never stored)
    const int o0 = og * 2;

    float acc[2][8];
#pragma unroll
    for (int lo = 0; lo < 2; ++lo)
#pragma unroll
        for (int b = 0; b < 8; ++b) acc[lo][b] = 0.f;

    const float* xq = x + 2 * q;
    const int ldsWaveBase = t & ~63;         // wave-uniform

    for (int h = 0; h < 2; ++h) {
        if (h) __syncthreads();              // prev compute's LDS reads done

        // ---- stage w[o0..o0+1][h*16..h*16+15][p][*][*] into LDS, lane-linear ----
#pragma unroll
        for (int j = 0; j < 18; ++j) {
            const int f = t + j * 512;       // 0..9215, linear LDS word index
            const int u = f >> 5;            // 0..287
            const int seg = u / 9;           // 0..31 (lo*16 + ii)
            int off = f - seg * WPAD;        // 0..287 within padded seg
            if (off > WSEG - 1) off = WSEG - 1;  // pad lanes dup-load, never read
            const int oi = o0 * CIN + h * 16 + seg + (seg & 16);  // (o0+lo)*32 + h*16 + ii
            const float* gp = wgt + (size_t)oi * WOI + p * WSEG + off;
            GLD_LDS(gp, &sm.w[j * 512 + ldsWaveBase]);
        }
        __syncthreads();                     // drains vmcnt -> staging visible

        // ---- compute: i = h*16 + ic ----
        const int i = h * 16 + ic;
        float wv[2][9];
        const int wb0 = ic * WPAD + q * 9;
        const int wb1 = (16 + ic) * WPAD + q * 9;
#pragma unroll
        for (int k = 0; k < 9; ++k) {
            wv[0][k] = sm.w[wb0 + k];
            wv[1][k] = sm.w[wb1 + k];
        }

        const float* xrow0 = xq + ((size_t)i * HH + 2 * p) * WW;
#pragma unroll
        for (int kh = 0; kh < 3; ++kh) {
            const float* xr = xrow0 + kh * WW;
#pragma unroll
            for (int b = 0; b < 8; ++b) {
                const float* xb = xr + (size_t)b * XB;
                const float2 a = *reinterpret_cast<const float2*>(xb);      // 2q,2q+1
                const float2 c = *reinterpret_cast<const float2*>(xb + 2);  // 2q+2,2q+3
#pragma unroll
                for (int lo = 0; lo < 2; ++lo)
                    acc[lo][b] += wv[lo][kh * 3 + 0] * a.x
                                + wv[lo][kh * 3 + 1] * a.y
                                + wv[lo][kh * 3 + 2] * c.x;
            }
        }
    }

    __syncthreads();                         // last w reads done before aliasing

    // ---- reduce 16 ic-partials per (q, lo, b) ----
#pragma unroll
    for (int lo = 0; lo < 2; ++lo)
#pragma unroll
        for (int b = 0; b < 8; ++b)
            sm.red[ic][qlane][lo * 8 + b] = acc[lo][b];
    __syncthreads();

    if (t < 496) {                           // 16 e x 31 q
        const int e  = t / 31;               // e = lo*8 + b
        const int qq = t - e * 31;
        float s = 0.f;
#pragma unroll
        for (int icc = 0; icc < 16; ++icc) s += sm.red[icc][qq][e];
        const int lo = e >> 3, b = e & 7;
        out[(((size_t)b * COUT + o0 + lo) * HO + p) * WO + qq] = s;
    }
}

extern "C" void kernel_launch(void* const* d_in, const int* in_sizes, int n_in,
                              void* d_out, int out_size, void* d_ws, size_t ws_size,
                              hipStream_t stream) {
    const float* x = (const float*)d_in[0];
    const float* w = (const float*)d_in[1];
    float* out = (float*)d_out;
    lc2d_kernel<<<dim3(HO * 16), dim3(512), 0, stream>>>(x, w, out);  // 31 p x 16 og
}